// Round 8
// baseline (242.867 us; speedup 1.0000x reference)
//
#include <hip/hip_runtime.h>

#define NPOS 65536   // 256*256

typedef __attribute__((ext_vector_type(8))) short bf16x8;
typedef __attribute__((ext_vector_type(4))) float f32x4;

#if __has_builtin(__builtin_amdgcn_exp2f)
#define EXP2F(x) __builtin_amdgcn_exp2f(x)
#else
#define EXP2F(x) __expf((x) * 0.6931471805599453f)
#endif
#if __has_builtin(__builtin_amdgcn_rcpf)
#define RCPF(x) __builtin_amdgcn_rcpf(x)
#else
#define RCPF(x) (1.0f / (x))
#endif

static __device__ __forceinline__ unsigned short f2bf(float f) {
  union { float f; unsigned int u; } v; v.f = f;
  unsigned int r = v.u + 0x7fffu + ((v.u >> 16) & 1u);
  return (unsigned short)(r >> 16);
}
static __device__ __forceinline__ float lo_bf(unsigned int u) {
  union { unsigned int u; float f; } v; v.u = u << 16; return v.f;
}
static __device__ __forceinline__ float hi_bf(unsigned int u) {
  union { unsigned int u; float f; } v; v.u = u & 0xffff0000u; return v.f;
}
// (hi.bf16_trunc << 16) | lo.bf16_trunc  — 1 instruction (v_perm_b32)
static __device__ __forceinline__ unsigned int permpack(float hi, float lo) {
  union { float f; unsigned int u; } a, b;
  a.f = hi; b.f = lo;
#if __has_builtin(__builtin_amdgcn_perm)
  return __builtin_amdgcn_perm(a.u, b.u, 0x07060302u);
#else
  return (a.u & 0xffff0000u) | (b.u >> 16);
#endif
}

// ---------------- K0: pack transposed bf16 weights ----------------
// Wq gets 1/sqrt(32) * log2(e) folded (softmax uses exp2, no max-sub).
__global__ void k_pack(const float* __restrict__ Wq, const float* __restrict__ Wk,
                       const float* __restrict__ Wv, const float* __restrict__ Wg,
                       const float* __restrict__ Wo,
                       ushort* __restrict__ WT, ushort* __restrict__ WoT) {
  int idx = blockIdx.x * blockDim.x + threadIdx.x;
  if (idx < 512 * 128) {
    int n = idx >> 7, k = idx & 127;
    int nn = n & 127;
    float val;
    if (n < 128)      val = Wq[k * 128 + nn] * (0.17677669529663687f * 1.4426950408889634f);
    else if (n < 256) val = Wk[k * 128 + nn];
    else if (n < 384) val = Wv[k * 128 + nn];
    else              val = Wg[k * 128 + nn];
    WT[idx] = f2bf(val);
  } else if (idx < 512 * 128 + 128 * 128) {
    int j = idx - 512 * 128;
    int n = j >> 7, k = j & 127;
    WoT[j] = f2bf(Wo[k * 128 + n]);
  }
}

// ---------------- K1: LN (store bf16 x_ln) + Wb bias projection ----------
__global__ __launch_bounds__(128, 4) void k_ln(
    const float* __restrict__ in, const float* __restrict__ gamma,
    const float* __restrict__ beta, const float* __restrict__ Wb,
    ushort* __restrict__ xln, ushort* __restrict__ biasB) {
  int t = threadIdx.x, wv = t >> 6, lane = t & 63;
  int n = lane & 15, g = lane >> 4;
  int myrow = blockIdx.x * 32 + wv * 16 + n;
  const float* rp = in + (size_t)myrow * 128;

  float xv[32];
  float sm = 0.f, ssm = 0.f;
  #pragma unroll
  for (int kc = 0; kc < 4; kc++)
    #pragma unroll
    for (int pr = 0; pr < 2; pr++) {
      float4 v = *(const float4*)(rp + kc * 32 + g * 8 + pr * 4);
      int o = kc * 8 + pr * 4;
      xv[o] = v.x; xv[o+1] = v.y; xv[o+2] = v.z; xv[o+3] = v.w;
      sm  += v.x + v.y + v.z + v.w;
      ssm += v.x*v.x + v.y*v.y + v.z*v.z + v.w*v.w;
    }
  sm  += __shfl_xor(sm, 16, 64);  sm  += __shfl_xor(sm, 32, 64);
  ssm += __shfl_xor(ssm, 16, 64); ssm += __shfl_xor(ssm, 32, 64);
  float mu  = sm * (1.0f / 128.0f);
  float var = ssm * (1.0f / 128.0f) - mu * mu;
  float rs  = rsqrtf(var + 1e-5f);
  float p0 = 0.f, p1 = 0.f, p2 = 0.f, p3 = 0.f;
  #pragma unroll
  for (int kc = 0; kc < 4; kc++)
    #pragma unroll
    for (int pr = 0; pr < 2; pr++) {
      int c0 = kc * 32 + g * 8 + pr * 4;
      float4 g4 = *(const float4*)(gamma + c0);
      float4 b4 = *(const float4*)(beta + c0);
      int o = kc * 8 + pr * 4;
      #pragma unroll
      for (int r = 0; r < 4; r++) {
        float xn = (xv[o + r] - mu) * rs * (&g4.x)[r] + (&b4.x)[r];
        xv[o + r] = xn;
        float4 w = ((const float4*)Wb)[c0 + r];
        p0 += xn * w.x; p1 += xn * w.y; p2 += xn * w.z; p3 += xn * w.w;
      }
    }
  #pragma unroll
  for (int kc = 0; kc < 4; kc++)
    #pragma unroll
    for (int pr = 0; pr < 2; pr++) {
      int o = kc * 8 + pr * 4;
      uint2 px;
      px.x = (unsigned int)f2bf(xv[o]) | ((unsigned int)f2bf(xv[o + 1]) << 16);
      px.y = (unsigned int)f2bf(xv[o + 2]) | ((unsigned int)f2bf(xv[o + 3]) << 16);
      *(uint2*)(xln + (size_t)myrow * 128 + kc * 32 + g * 8 + pr * 4) = px;
    }
  p0 += __shfl_xor(p0, 16, 64); p0 += __shfl_xor(p0, 32, 64);
  p1 += __shfl_xor(p1, 16, 64); p1 += __shfl_xor(p1, 32, 64);
  p2 += __shfl_xor(p2, 16, 64); p2 += __shfl_xor(p2, 32, 64);
  p3 += __shfl_xor(p3, 16, 64); p3 += __shfl_xor(p3, 32, 64);
  if (g == 0) {
    const float l2e = 1.4426950408889634f;
    biasB[0 * NPOS + myrow] = f2bf(p0 * l2e);
    biasB[1 * NPOS + myrow] = f2bf(p1 * l2e);
    biasB[2 * NPOS + myrow] = f2bf(p2 * l2e);
    biasB[3 * NPOS + myrow] = f2bf(p3 * l2e);
  }
}

// ---------------- K2: head-slice proj + attention + gate ----------------
// R7: occupancy play. PV reverted to R5's LDS round-trip (VGPR back <=~70).
// LDS cut to 53760B -> 3 blocks/CU (was 2): (a) P-stage aliases the consumed
// Q rows in qstg (DS pipe in-order per wave: bq for tile tt is read into
// registers before PV writes rows [tt*16,tt*16+16)); (b) KS/QS 40->36
// (72B rows, bank map 18n+4g fully distinct; K/Q/P reads become 2x b64
// since 72B rows aren't 16B aligned). VS stays 264 for b128 V reads.
#define KS 36    // Klds row stride (ushorts; 72B)
#define VS 264   // VTlds row stride (ushorts; keys 256 + 8 pad, 16B-aligned)
#define QS 36    // qstg row stride (ushorts; 72B) — also the P-stage stride
__global__ __launch_bounds__(512, 3) void k_attn2(
    const ushort* __restrict__ xln, const ushort* __restrict__ WT,
    const float* __restrict__ bg, const ushort* __restrict__ biasB,
    ushort* __restrict__ gctx) {
  __shared__ __align__(16) ushort Klds[256 * KS];    // 18432 B
  __shared__ __align__(16) ushort VTlds[32 * VS];    // 16896 B
  __shared__ __align__(16) ushort qstg[8][32 * QS];  // 18432 B (Q, then P)
  int i = blockIdx.x & 255, h = blockIdx.x >> 8;     // XCD-friendly remap
  int t = threadIdx.x, wv = t >> 6, lane = t & 63;
  int n = lane & 15, g = lane >> 4;
  int r0 = wv * 32;

  // ---- phase A: load LN'd rows as MFMA a-frags (bf16, direct) ----
  bf16x8 a[2][4];
  const ushort* xb = xln + ((size_t)i * 256 + r0) * 128;
  #pragma unroll
  for (int c = 0; c < 2; c++)
    #pragma unroll
    for (int kc = 0; kc < 4; kc++)
      a[c][kc] = *(const bf16x8*)(xb + (size_t)(c * 16 + n) * 128 + kc * 32 + g * 8);

  // ---- phase A2: 4 head-slice projections (32 cols each) ----
  f32x4 gs[2][2];   // gate (sigmoid applied), lane-mapped same as PV output
  #pragma unroll
  for (int sect = 0; sect < 4; sect++) {
    bf16x8 b[2][4];
    #pragma unroll
    for (int ntl = 0; ntl < 2; ntl++)
      #pragma unroll
      for (int kc = 0; kc < 4; kc++)
        b[ntl][kc] = *(const bf16x8*)(WT + (size_t)(sect * 128 + h * 32 + ntl * 16 + n) * 128 + kc * 32 + g * 8);
    #pragma unroll
    for (int c = 0; c < 2; c++) {
      f32x4 acc[2];
      #pragma unroll
      for (int ntl = 0; ntl < 2; ntl++) {
        f32x4 cc = {0.f, 0.f, 0.f, 0.f};
        #pragma unroll
        for (int kc = 0; kc < 4; kc++)
          cc = __builtin_amdgcn_mfma_f32_16x16x32_bf16(a[c][kc], b[ntl][kc], cc, 0, 0, 0);
        acc[ntl] = cc;
      }
      // acc[ntl][r] = proj[row r0+c*16+g*4+r][dim ntl*16+n] (head-local dim)
      if (sect == 0) {          // Q -> wave-private LDS [query][dim]
        #pragma unroll
        for (int ntl = 0; ntl < 2; ntl++)
          #pragma unroll
          for (int r = 0; r < 4; r++)
            qstg[wv][(c * 16 + g * 4 + r) * QS + ntl * 16 + n] = f2bf(acc[ntl][r]);
      } else if (sect == 1) {   // K -> shared LDS [key][dim]
        #pragma unroll
        for (int ntl = 0; ntl < 2; ntl++)
          #pragma unroll
          for (int r = 0; r < 4; r++)
            Klds[(r0 + c * 16 + g * 4 + r) * KS + ntl * 16 + n] = f2bf(acc[ntl][r]);
      } else if (sect == 2) {   // V -> shared LDS transposed [dim][key]
        #pragma unroll
        for (int ntl = 0; ntl < 2; ntl++) {
          uint2 vp;
          vp.x = (unsigned int)f2bf(acc[ntl][0]) | ((unsigned int)f2bf(acc[ntl][1]) << 16);
          vp.y = (unsigned int)f2bf(acc[ntl][2]) | ((unsigned int)f2bf(acc[ntl][3]) << 16);
          *(uint2*)(&VTlds[(ntl * 16 + n) * VS + r0 + c * 16 + g * 4]) = vp;
        }
      } else {                  // gate: keep in registers
        #pragma unroll
        for (int ntl = 0; ntl < 2; ntl++)
          #pragma unroll
          for (int r = 0; r < 4; r++)
            gs[c][ntl][r] = 1.0f / (1.0f + __expf(-(acc[ntl][r] + bg[h * 32 + ntl * 16 + n])));
      }
    }
  }
  __syncthreads();

  // ---- phase B: attention for the wave's 32 queries (2 tiles of 16) ----
  const ushort* bb = biasB + (size_t)h * NPOS;
  #pragma unroll
  for (int tt = 0; tt < 2; tt++) {
    int j0 = r0 + tt * 16;
    // Q fragment: two b64 reads (72B rows, conflict-free 18n+4g bank map)
    union { bf16x8 v; uint2 u[2]; } bq;
    bq.u[0] = *(const uint2*)(&qstg[wv][(tt * 16 + n) * QS + g * 8]);
    bq.u[1] = *(const uint2*)(&qstg[wv][(tt * 16 + n) * QS + g * 8 + 4]);
    // P-stage aliases the 16 Q rows just consumed (wave-private, in-order DS)
    ushort* Pw = &qstg[wv][tt * 16 * QS];
    // hoist all 16 bias loads (independent, one vmcnt train)
    uint2 bv[16];
    #pragma unroll
    for (int kt = 0; kt < 16; kt++)
      bv[kt] = *(const uint2*)(bb + (size_t)(j0 + n) * 256 + kt * 16 + g * 4);
    f32x4 s[16];
    #pragma unroll
    for (int kt = 0; kt < 16; kt++) {
      union { bf16x8 v; uint2 u[2]; } ak;
      ak.u[0] = *(const uint2*)(&Klds[(kt * 16 + n) * KS + g * 8]);
      ak.u[1] = *(const uint2*)(&Klds[(kt * 16 + n) * KS + g * 8 + 4]);
      f32x4 cc;
      cc[0] = lo_bf(bv[kt].x); cc[1] = hi_bf(bv[kt].x);
      cc[2] = lo_bf(bv[kt].y); cc[3] = hi_bf(bv[kt].y);
      s[kt] = __builtin_amdgcn_mfma_f32_16x16x32_bf16(ak.v, bq.v, cc, 0, 0, 0);
    }
    // softmax: exp2 (log2e pre-folded), no max-sub (scores bounded ~|2|)
    f32x4 a4 = {0.f, 0.f, 0.f, 0.f};
    #pragma unroll
    for (int kt = 0; kt < 16; kt++) {
      #pragma unroll
      for (int r = 0; r < 4; r++) s[kt][r] = EXP2F(s[kt][r]);
      a4 += s[kt];
    }
    float smm = (a4[0] + a4[1]) + (a4[2] + a4[3]);
    smm += __shfl_xor(smm, 16, 64);
    smm += __shfl_xor(smm, 32, 64);
    float inv = RCPF(smm);
    // PV via wave-private LDS round trip (R5-verified; in-order DS pipe)
    f32x4 ctx0 = {0.f, 0.f, 0.f, 0.f}, ctx1 = {0.f, 0.f, 0.f, 0.f};
    #pragma unroll
    for (int c8 = 0; c8 < 8; c8++) {
      #pragma unroll
      for (int t2 = 0; t2 < 2; t2++) {
        int kt = c8 * 2 + t2;
        uint2 pp;
        pp.x = permpack(s[kt][1] * inv, s[kt][0] * inv);
        pp.y = permpack(s[kt][3] * inv, s[kt][2] * inv);
        *(uint2*)(&Pw[n * QS + t2 * 16 + g * 4]) = pp;   // row=query n, 4 keys
      }
      union { bf16x8 v; uint2 u[2]; } ap;
      ap.u[0] = *(const uint2*)(&Pw[n * QS + g * 8]);
      ap.u[1] = *(const uint2*)(&Pw[n * QS + g * 8 + 4]);
      bf16x8 v0 = *(const bf16x8*)(&VTlds[(size_t)n * VS + c8 * 32 + g * 8]);
      bf16x8 v1 = *(const bf16x8*)(&VTlds[(size_t)(16 + n) * VS + c8 * 32 + g * 8]);
      ctx0 = __builtin_amdgcn_mfma_f32_16x16x32_bf16(ap.v, v0, ctx0, 0, 0, 0);
      ctx1 = __builtin_amdgcn_mfma_f32_16x16x32_bf16(ap.v, v1, ctx1, 0, 0, 0);
    }
    // gate in registers (identical lane mapping), direct global store
    #pragma unroll
    for (int r = 0; r < 4; r++) {
      size_t pos = (size_t)i * 256 + j0 + g * 4 + r;
      gctx[pos * 128 + h * 32 + n]      = f2bf(ctx0[r] * gs[tt][0][r]);
      gctx[pos * 128 + h * 32 + 16 + n] = f2bf(ctx1[r] * gs[tt][1][r]);
    }
  }
}

// ---------------- K3: out-proj + bias + residual ----------------
// barrier-free, LDS-free. Operand-swapped MFMA (A=Wo fragment, B=ctx
// fragment) -> lane(n,g) holds out[row0+n][ntl*16+g*4..+3] -> direct
// coalesced f32x4 residual-add store. 256 thr, 64 rows/block, grid 1024.
__global__ __launch_bounds__(256, 4) void k_out(
    const ushort* __restrict__ gctx, const ushort* __restrict__ WoT,
    const float* __restrict__ bo, const float* __restrict__ in0,
    float* __restrict__ out) {
  int t = threadIdx.x, wv = t >> 6, lane = t & 63;
  int n = lane & 15, g = lane >> 4;
  int row0 = blockIdx.x * 64 + wv * 16;
  bf16x8 cfr[4];
  #pragma unroll
  for (int kc = 0; kc < 4; kc++)
    cfr[kc] = *(const bf16x8*)(gctx + (size_t)(row0 + n) * 128 + kc * 32 + g * 8);
  size_t rowg = (size_t)row0 + n;
  #pragma unroll
  for (int ntl = 0; ntl < 8; ntl++) {
    f32x4 acc = {0.f, 0.f, 0.f, 0.f};
    #pragma unroll
    for (int kc = 0; kc < 4; kc++) {
      bf16x8 wo = *(const bf16x8*)(WoT + (size_t)(ntl * 16 + n) * 128 + kc * 32 + g * 8);
      acc = __builtin_amdgcn_mfma_f32_16x16x32_bf16(wo, cfr[kc], acc, 0, 0, 0);
    }
    f32x4 b4 = *(const f32x4*)(bo + ntl * 16 + g * 4);
    size_t o = rowg * 128 + ntl * 16 + g * 4;
    f32x4 r4 = *(const f32x4*)(in0 + o);
    acc[0] += b4[0] + r4[0]; acc[1] += b4[1] + r4[1];
    acc[2] += b4[2] + r4[2]; acc[3] += b4[3] + r4[3];
    *(f32x4*)(out + o) = acc;
  }
}

extern "C" void kernel_launch(void* const* d_in, const int* in_sizes, int n_in,
                              void* d_out, int out_size, void* d_ws, size_t ws_size,
                              hipStream_t stream) {
  const float* in0   = (const float*)d_in[0];
  const float* gamma = (const float*)d_in[1];
  const float* beta  = (const float*)d_in[2];
  const float* Wq    = (const float*)d_in[3];
  const float* Wk    = (const float*)d_in[4];
  const float* Wv    = (const float*)d_in[5];
  const float* Wb    = (const float*)d_in[6];
  const float* Wg    = (const float*)d_in[7];
  const float* bg    = (const float*)d_in[8];
  const float* Wo    = (const float*)d_in[9];
  const float* bo    = (const float*)d_in[10];
  float* out = (float*)d_out;
  char* ws = (char*)d_ws;

  const size_t MB = 1024 * 1024;
  ushort* gctx  = (ushort*)(ws);              // 16 MB: [pos][128]
  ushort* xln   = (ushort*)(ws + 16 * MB);    // 16 MB: LN'd x, bf16 [pos][128]
  ushort* biasB = (ushort*)(ws + 32 * MB);    // 512 KB: [h][j*256+k] * log2e
  ushort* WT    = (ushort*)(ws + 33 * MB);    // 128 KB
  ushort* WoT   = (ushort*)(ws + 33 * MB + 128 * 1024);  // 32 KB

  k_pack <<<320, 256, 0, stream>>>(Wq, Wk, Wv, Wg, Wo, WT, WoT);
  k_ln   <<<2048, 128, 0, stream>>>(in0, gamma, beta, Wb, xln, biasB);
  k_attn2<<<1024, 512, 0, stream>>>(xln, WT, bg, biasB, gctx);
  k_out  <<<1024, 256, 0, stream>>>(gctx, WoT, bo, in0, out);
}

// Round 9
// 219.621 us; speedup vs baseline: 1.1059x; 1.1059x over previous
//
#include <hip/hip_runtime.h>

#define NPOS 65536   // 256*256

typedef __attribute__((ext_vector_type(8))) short bf16x8;
typedef __attribute__((ext_vector_type(4))) float f32x4;

#if __has_builtin(__builtin_amdgcn_exp2f)
#define EXP2F(x) __builtin_amdgcn_exp2f(x)
#else
#define EXP2F(x) __expf((x) * 0.6931471805599453f)
#endif
#if __has_builtin(__builtin_amdgcn_rcpf)
#define RCPF(x) __builtin_amdgcn_rcpf(x)
#else
#define RCPF(x) (1.0f / (x))
#endif

static __device__ __forceinline__ unsigned short f2bf(float f) {
  union { float f; unsigned int u; } v; v.f = f;
  unsigned int r = v.u + 0x7fffu + ((v.u >> 16) & 1u);
  return (unsigned short)(r >> 16);
}
static __device__ __forceinline__ float lo_bf(unsigned int u) {
  union { unsigned int u; float f; } v; v.u = u << 16; return v.f;
}
static __device__ __forceinline__ float hi_bf(unsigned int u) {
  union { unsigned int u; float f; } v; v.u = u & 0xffff0000u; return v.f;
}
// (hi.bf16_trunc << 16) | lo.bf16_trunc  — 1 instruction (v_perm_b32)
static __device__ __forceinline__ unsigned int permpack(float hi, float lo) {
  union { float f; unsigned int u; } a, b;
  a.f = hi; b.f = lo;
#if __has_builtin(__builtin_amdgcn_perm)
  return __builtin_amdgcn_perm(a.u, b.u, 0x07060302u);
#else
  return (a.u & 0xffff0000u) | (b.u >> 16);
#endif
}

// ---------------- K0: pack transposed bf16 weights ----------------
// Wq gets 1/sqrt(32) * log2(e) folded (softmax uses exp2, no max-sub).
__global__ void k_pack(const float* __restrict__ Wq, const float* __restrict__ Wk,
                       const float* __restrict__ Wv, const float* __restrict__ Wg,
                       const float* __restrict__ Wo,
                       ushort* __restrict__ WT, ushort* __restrict__ WoT) {
  int idx = blockIdx.x * blockDim.x + threadIdx.x;
  if (idx < 512 * 128) {
    int n = idx >> 7, k = idx & 127;
    int nn = n & 127;
    float val;
    if (n < 128)      val = Wq[k * 128 + nn] * (0.17677669529663687f * 1.4426950408889634f);
    else if (n < 256) val = Wk[k * 128 + nn];
    else if (n < 384) val = Wv[k * 128 + nn];
    else              val = Wg[k * 128 + nn];
    WT[idx] = f2bf(val);
  } else if (idx < 512 * 128 + 128 * 128) {
    int j = idx - 512 * 128;
    int n = j >> 7, k = j & 127;
    WoT[j] = f2bf(Wo[k * 128 + n]);
  }
}

// ---------------- K1: LN (store bf16 x_ln) + Wb bias projection ----------
__global__ __launch_bounds__(128, 4) void k_ln(
    const float* __restrict__ in, const float* __restrict__ gamma,
    const float* __restrict__ beta, const float* __restrict__ Wb,
    ushort* __restrict__ xln, ushort* __restrict__ biasB) {
  int t = threadIdx.x, wv = t >> 6, lane = t & 63;
  int n = lane & 15, g = lane >> 4;
  int myrow = blockIdx.x * 32 + wv * 16 + n;
  const float* rp = in + (size_t)myrow * 128;

  float xv[32];
  float sm = 0.f, ssm = 0.f;
  #pragma unroll
  for (int kc = 0; kc < 4; kc++)
    #pragma unroll
    for (int pr = 0; pr < 2; pr++) {
      float4 v = *(const float4*)(rp + kc * 32 + g * 8 + pr * 4);
      int o = kc * 8 + pr * 4;
      xv[o] = v.x; xv[o+1] = v.y; xv[o+2] = v.z; xv[o+3] = v.w;
      sm  += v.x + v.y + v.z + v.w;
      ssm += v.x*v.x + v.y*v.y + v.z*v.z + v.w*v.w;
    }
  sm  += __shfl_xor(sm, 16, 64);  sm  += __shfl_xor(sm, 32, 64);
  ssm += __shfl_xor(ssm, 16, 64); ssm += __shfl_xor(ssm, 32, 64);
  float mu  = sm * (1.0f / 128.0f);
  float var = ssm * (1.0f / 128.0f) - mu * mu;
  float rs  = rsqrtf(var + 1e-5f);
  float p0 = 0.f, p1 = 0.f, p2 = 0.f, p3 = 0.f;
  #pragma unroll
  for (int kc = 0; kc < 4; kc++)
    #pragma unroll
    for (int pr = 0; pr < 2; pr++) {
      int c0 = kc * 32 + g * 8 + pr * 4;
      float4 g4 = *(const float4*)(gamma + c0);
      float4 b4 = *(const float4*)(beta + c0);
      int o = kc * 8 + pr * 4;
      #pragma unroll
      for (int r = 0; r < 4; r++) {
        float xn = (xv[o + r] - mu) * rs * (&g4.x)[r] + (&b4.x)[r];
        xv[o + r] = xn;
        float4 w = ((const float4*)Wb)[c0 + r];
        p0 += xn * w.x; p1 += xn * w.y; p2 += xn * w.z; p3 += xn * w.w;
      }
    }
  #pragma unroll
  for (int kc = 0; kc < 4; kc++)
    #pragma unroll
    for (int pr = 0; pr < 2; pr++) {
      int o = kc * 8 + pr * 4;
      uint2 px;
      px.x = (unsigned int)f2bf(xv[o]) | ((unsigned int)f2bf(xv[o + 1]) << 16);
      px.y = (unsigned int)f2bf(xv[o + 2]) | ((unsigned int)f2bf(xv[o + 3]) << 16);
      *(uint2*)(xln + (size_t)myrow * 128 + kc * 32 + g * 8 + pr * 4) = px;
    }
  p0 += __shfl_xor(p0, 16, 64); p0 += __shfl_xor(p0, 32, 64);
  p1 += __shfl_xor(p1, 16, 64); p1 += __shfl_xor(p1, 32, 64);
  p2 += __shfl_xor(p2, 16, 64); p2 += __shfl_xor(p2, 32, 64);
  p3 += __shfl_xor(p3, 16, 64); p3 += __shfl_xor(p3, 32, 64);
  if (g == 0) {
    const float l2e = 1.4426950408889634f;
    biasB[0 * NPOS + myrow] = f2bf(p0 * l2e);
    biasB[1 * NPOS + myrow] = f2bf(p1 * l2e);
    biasB[2 * NPOS + myrow] = f2bf(p2 * l2e);
    biasB[3 * NPOS + myrow] = f2bf(p3 * l2e);
  }
}

// ---------------- K2: head-slice proj + attention + gate ----------------
// R8: R5-measured structure (75.4us: LDS PV round-trip, KS=40/VS=264 b128,
// launch_bounds(512,2) — NEVER (.,3): it forced VGPR 84 + scratch spills,
// hbm 42->198MB, R7) with ONE cut: qstg deleted (-20480B LDS). Q stays in
// registers: Q-proj is operand-SWAPPED (mfma(W,x)) so lane(n,g) holds
// Q[own query row n][dims g*4..+3, 16+g*4..+3] — packed to one bf16x8 per
// tile. QK^T uses the same dim permutation on K (two b64 reads from Klds at
// dim offsets g*4 and 16+g*4), so S is bit-identical. LDS 47616B -> 3
// blocks/CU (was 2).
#define KS 40    // Klds row stride (ushorts; 80B, 16B-aligned)
#define VS 264   // VTlds row stride (ushorts; keys 256 + 8 pad, 16B-aligned)
#define PST 40   // P-stage row stride (ushorts; 80B, 16B-aligned)
__global__ __launch_bounds__(512, 2) void k_attn2(
    const ushort* __restrict__ xln, const ushort* __restrict__ WT,
    const float* __restrict__ bg, const ushort* __restrict__ biasB,
    ushort* __restrict__ gctx) {
  __shared__ __align__(16) ushort Klds[256 * KS];    // 20480 B
  __shared__ __align__(16) ushort VTlds[32 * VS];    // 16896 B
  __shared__ __align__(16) ushort pstg[8][16 * PST]; // 10240 B
  int i = blockIdx.x & 255, h = blockIdx.x >> 8;     // XCD-friendly remap
  int t = threadIdx.x, wv = t >> 6, lane = t & 63;
  int n = lane & 15, g = lane >> 4;
  int r0 = wv * 32;

  // ---- phase A: load LN'd rows as MFMA a-frags (bf16, direct) ----
  bf16x8 a[2][4];
  const ushort* xb = xln + ((size_t)i * 256 + r0) * 128;
  #pragma unroll
  for (int c = 0; c < 2; c++)
    #pragma unroll
    for (int kc = 0; kc < 4; kc++)
      a[c][kc] = *(const bf16x8*)(xb + (size_t)(c * 16 + n) * 128 + kc * 32 + g * 8);

  // ---- phase A2: 4 head-slice projections (32 cols each) ----
  bf16x8 qreg[2];   // Q[own row n][dims g*4..+3 | 16+g*4..+3], per tile
  f32x4 gs[2][2];   // gate (sigmoid applied), lane-mapped same as PV output
  #pragma unroll
  for (int sect = 0; sect < 4; sect++) {
    bf16x8 b[2][4];
    #pragma unroll
    for (int ntl = 0; ntl < 2; ntl++)
      #pragma unroll
      for (int kc = 0; kc < 4; kc++)
        b[ntl][kc] = *(const bf16x8*)(WT + (size_t)(sect * 128 + h * 32 + ntl * 16 + n) * 128 + kc * 32 + g * 8);
    #pragma unroll
    for (int c = 0; c < 2; c++) {
      f32x4 acc[2];
      #pragma unroll
      for (int ntl = 0; ntl < 2; ntl++) {
        f32x4 cc = {0.f, 0.f, 0.f, 0.f};
        #pragma unroll
        for (int kc = 0; kc < 4; kc++) {
          if (sect == 0)   // swapped: D[dim][row] -> lane holds own-row dims
            cc = __builtin_amdgcn_mfma_f32_16x16x32_bf16(b[ntl][kc], a[c][kc], cc, 0, 0, 0);
          else
            cc = __builtin_amdgcn_mfma_f32_16x16x32_bf16(a[c][kc], b[ntl][kc], cc, 0, 0, 0);
        }
        acc[ntl] = cc;
      }
      if (sect == 0) {
        // acc[ntl][r] = Q[row r0+c*16+n][dim ntl*16+g*4+r] -> pack to regs
        union { bf16x8 v; uint2 u[2]; } q;
        q.u[0].x = permpack(acc[0][1], acc[0][0]);
        q.u[0].y = permpack(acc[0][3], acc[0][2]);
        q.u[1].x = permpack(acc[1][1], acc[1][0]);
        q.u[1].y = permpack(acc[1][3], acc[1][2]);
        qreg[c] = q.v;
      } else if (sect == 1) {   // K -> shared LDS [key][dim]
        #pragma unroll
        for (int ntl = 0; ntl < 2; ntl++)
          #pragma unroll
          for (int r = 0; r < 4; r++)
            Klds[(r0 + c * 16 + g * 4 + r) * KS + ntl * 16 + n] = f2bf(acc[ntl][r]);
      } else if (sect == 2) {   // V -> shared LDS transposed [dim][key]
        #pragma unroll
        for (int ntl = 0; ntl < 2; ntl++) {
          uint2 vp;
          vp.x = (unsigned int)f2bf(acc[ntl][0]) | ((unsigned int)f2bf(acc[ntl][1]) << 16);
          vp.y = (unsigned int)f2bf(acc[ntl][2]) | ((unsigned int)f2bf(acc[ntl][3]) << 16);
          *(uint2*)(&VTlds[(ntl * 16 + n) * VS + r0 + c * 16 + g * 4]) = vp;
        }
      } else {                  // gate: keep in registers
        #pragma unroll
        for (int ntl = 0; ntl < 2; ntl++)
          #pragma unroll
          for (int r = 0; r < 4; r++)
            gs[c][ntl][r] = 1.0f / (1.0f + __expf(-(acc[ntl][r] + bg[h * 32 + ntl * 16 + n])));
      }
    }
  }
  __syncthreads();

  // ---- phase B: attention for the wave's 32 queries (2 tiles of 16) ----
  const ushort* bb = biasB + (size_t)h * NPOS;
  ushort* Pw = pstg[wv];
  #pragma unroll
  for (int tt = 0; tt < 2; tt++) {
    int j0 = r0 + tt * 16;
    // hoist all 16 bias loads (independent, one vmcnt train)
    uint2 bv[16];
    #pragma unroll
    for (int kt = 0; kt < 16; kt++)
      bv[kt] = *(const uint2*)(bb + (size_t)(j0 + n) * 256 + kt * 16 + g * 4);
    f32x4 s[16];
    #pragma unroll
    for (int kt = 0; kt < 16; kt++) {
      // K at the same permuted dim order as qreg: dims g*4..+3 and 16+g*4..+3
      union { bf16x8 v; uint2 u[2]; } ak;
      ak.u[0] = *(const uint2*)(&Klds[(kt * 16 + n) * KS + g * 4]);
      ak.u[1] = *(const uint2*)(&Klds[(kt * 16 + n) * KS + 16 + g * 4]);
      f32x4 cc;
      cc[0] = lo_bf(bv[kt].x); cc[1] = hi_bf(bv[kt].x);
      cc[2] = lo_bf(bv[kt].y); cc[3] = hi_bf(bv[kt].y);
      s[kt] = __builtin_amdgcn_mfma_f32_16x16x32_bf16(ak.v, qreg[tt], cc, 0, 0, 0);
    }
    // softmax: exp2 (log2e pre-folded), no max-sub (scores bounded ~|2|)
    f32x4 a4 = {0.f, 0.f, 0.f, 0.f};
    #pragma unroll
    for (int kt = 0; kt < 16; kt++) {
      #pragma unroll
      for (int r = 0; r < 4; r++) s[kt][r] = EXP2F(s[kt][r]);
      a4 += s[kt];
    }
    float smm = (a4[0] + a4[1]) + (a4[2] + a4[3]);
    smm += __shfl_xor(smm, 16, 64);
    smm += __shfl_xor(smm, 32, 64);
    float inv = RCPF(smm);
    // PV via wave-private LDS round trip (R5-verified; in-order DS pipe)
    f32x4 ctx0 = {0.f, 0.f, 0.f, 0.f}, ctx1 = {0.f, 0.f, 0.f, 0.f};
    #pragma unroll
    for (int c8 = 0; c8 < 8; c8++) {
      #pragma unroll
      for (int t2 = 0; t2 < 2; t2++) {
        int kt = c8 * 2 + t2;
        uint2 pp;
        pp.x = permpack(s[kt][1] * inv, s[kt][0] * inv);
        pp.y = permpack(s[kt][3] * inv, s[kt][2] * inv);
        *(uint2*)(&Pw[n * PST + t2 * 16 + g * 4]) = pp;   // row=query n, 4 keys
      }
      bf16x8 ap = *(const bf16x8*)(&Pw[n * PST + g * 8]);
      bf16x8 v0 = *(const bf16x8*)(&VTlds[(size_t)n * VS + c8 * 32 + g * 8]);
      bf16x8 v1 = *(const bf16x8*)(&VTlds[(size_t)(16 + n) * VS + c8 * 32 + g * 8]);
      ctx0 = __builtin_amdgcn_mfma_f32_16x16x32_bf16(ap, v0, ctx0, 0, 0, 0);
      ctx1 = __builtin_amdgcn_mfma_f32_16x16x32_bf16(ap, v1, ctx1, 0, 0, 0);
    }
    // gate in registers (identical lane mapping), direct global store
    #pragma unroll
    for (int r = 0; r < 4; r++) {
      size_t pos = (size_t)i * 256 + j0 + g * 4 + r;
      gctx[pos * 128 + h * 32 + n]      = f2bf(ctx0[r] * gs[tt][0][r]);
      gctx[pos * 128 + h * 32 + 16 + n] = f2bf(ctx1[r] * gs[tt][1][r]);
    }
  }
}

// ---------------- K3: out-proj + bias + residual ----------------
// barrier-free, LDS-free. Operand-swapped MFMA (A=Wo fragment, B=ctx
// fragment) -> lane(n,g) holds out[row0+n][ntl*16+g*4..+3] -> direct
// coalesced f32x4 residual-add store. 256 thr, 64 rows/block, grid 1024.
__global__ __launch_bounds__(256, 4) void k_out(
    const ushort* __restrict__ gctx, const ushort* __restrict__ WoT,
    const float* __restrict__ bo, const float* __restrict__ in0,
    float* __restrict__ out) {
  int t = threadIdx.x, wv = t >> 6, lane = t & 63;
  int n = lane & 15, g = lane >> 4;
  int row0 = blockIdx.x * 64 + wv * 16;
  bf16x8 cfr[4];
  #pragma unroll
  for (int kc = 0; kc < 4; kc++)
    cfr[kc] = *(const bf16x8*)(gctx + (size_t)(row0 + n) * 128 + kc * 32 + g * 8);
  size_t rowg = (size_t)row0 + n;
  #pragma unroll
  for (int ntl = 0; ntl < 8; ntl++) {
    f32x4 acc = {0.f, 0.f, 0.f, 0.f};
    #pragma unroll
    for (int kc = 0; kc < 4; kc++) {
      bf16x8 wo = *(const bf16x8*)(WoT + (size_t)(ntl * 16 + n) * 128 + kc * 32 + g * 8);
      acc = __builtin_amdgcn_mfma_f32_16x16x32_bf16(wo, cfr[kc], acc, 0, 0, 0);
    }
    f32x4 b4 = *(const f32x4*)(bo + ntl * 16 + g * 4);
    size_t o = rowg * 128 + ntl * 16 + g * 4;
    f32x4 r4 = *(const f32x4*)(in0 + o);
    acc[0] += b4[0] + r4[0]; acc[1] += b4[1] + r4[1];
    acc[2] += b4[2] + r4[2]; acc[3] += b4[3] + r4[3];
    *(f32x4*)(out + o) = acc;
  }
}

extern "C" void kernel_launch(void* const* d_in, const int* in_sizes, int n_in,
                              void* d_out, int out_size, void* d_ws, size_t ws_size,
                              hipStream_t stream) {
  const float* in0   = (const float*)d_in[0];
  const float* gamma = (const float*)d_in[1];
  const float* beta  = (const float*)d_in[2];
  const float* Wq    = (const float*)d_in[3];
  const float* Wk    = (const float*)d_in[4];
  const float* Wv    = (const float*)d_in[5];
  const float* Wb    = (const float*)d_in[6];
  const float* Wg    = (const float*)d_in[7];
  const float* bg    = (const float*)d_in[8];
  const float* Wo    = (const float*)d_in[9];
  const float* bo    = (const float*)d_in[10];
  float* out = (float*)d_out;
  char* ws = (char*)d_ws;

  const size_t MB = 1024 * 1024;
  ushort* gctx  = (ushort*)(ws);              // 16 MB: [pos][128]
  ushort* xln   = (ushort*)(ws + 16 * MB);    // 16 MB: LN'd x, bf16 [pos][128]
  ushort* biasB = (ushort*)(ws + 32 * MB);    // 512 KB: [h][j*256+k] * log2e
  ushort* WT    = (ushort*)(ws + 33 * MB);    // 128 KB
  ushort* WoT   = (ushort*)(ws + 33 * MB + 128 * 1024);  // 32 KB

  k_pack <<<320, 256, 0, stream>>>(Wq, Wk, Wv, Wg, Wo, WT, WoT);
  k_ln   <<<2048, 128, 0, stream>>>(in0, gamma, beta, Wb, xln, biasB);
  k_attn2<<<1024, 512, 0, stream>>>(xln, WT, bg, biasB, gctx);
  k_out  <<<1024, 256, 0, stream>>>(gctx, WoT, bo, in0, out);
}

// Round 10
// 201.180 us; speedup vs baseline: 1.2072x; 1.0917x over previous
//
#include <hip/hip_runtime.h>

#define NPOS 65536   // 256*256

typedef __attribute__((ext_vector_type(8))) short bf16x8;
typedef __attribute__((ext_vector_type(4))) float f32x4;

#if __has_builtin(__builtin_amdgcn_exp2f)
#define EXP2F(x) __builtin_amdgcn_exp2f(x)
#else
#define EXP2F(x) __expf((x) * 0.6931471805599453f)
#endif
#if __has_builtin(__builtin_amdgcn_rcpf)
#define RCPF(x) __builtin_amdgcn_rcpf(x)
#else
#define RCPF(x) (1.0f / (x))
#endif

static __device__ __forceinline__ unsigned short f2bf(float f) {
  union { float f; unsigned int u; } v; v.f = f;
  unsigned int r = v.u + 0x7fffu + ((v.u >> 16) & 1u);
  return (unsigned short)(r >> 16);
}
static __device__ __forceinline__ float lo_bf(unsigned int u) {
  union { unsigned int u; float f; } v; v.u = u << 16; return v.f;
}
static __device__ __forceinline__ float hi_bf(unsigned int u) {
  union { unsigned int u; float f; } v; v.u = u & 0xffff0000u; return v.f;
}
// (hi.bf16_trunc << 16) | lo.bf16_trunc  — 1 instruction (v_perm_b32)
static __device__ __forceinline__ unsigned int permpack(float hi, float lo) {
  union { float f; unsigned int u; } a, b;
  a.f = hi; b.f = lo;
#if __has_builtin(__builtin_amdgcn_perm)
  return __builtin_amdgcn_perm(a.u, b.u, 0x07060302u);
#else
  return (a.u & 0xffff0000u) | (b.u >> 16);
#endif
}

// ---------------- K1: fused {LN + Wb bias + xln store} | {weight pack} ----
// R9: k_pack folded in as blocks >= 2048 (640 blocks x 128 thr = 81920 elems)
// — one fewer dispatch. LN path: xln stored as 16B uint4 (was 2x 8B).
__global__ __launch_bounds__(128, 4) void k_lnpack(
    const float* __restrict__ in, const float* __restrict__ gamma,
    const float* __restrict__ beta, const float* __restrict__ Wb,
    const float* __restrict__ Wq, const float* __restrict__ Wk,
    const float* __restrict__ Wv, const float* __restrict__ Wg,
    const float* __restrict__ Wo,
    ushort* __restrict__ xln, ushort* __restrict__ biasB,
    ushort* __restrict__ WT, ushort* __restrict__ WoT) {
  int t = threadIdx.x;
  if (blockIdx.x >= 2048) {
    // ---- pack path: transposed bf16 weights ----
    int idx = (blockIdx.x - 2048) * 128 + t;
    if (idx < 512 * 128) {
      int n = idx >> 7, k = idx & 127;
      int nn = n & 127;
      float val;
      if (n < 128)      val = Wq[k * 128 + nn] * (0.17677669529663687f * 1.4426950408889634f);
      else if (n < 256) val = Wk[k * 128 + nn];
      else if (n < 384) val = Wv[k * 128 + nn];
      else              val = Wg[k * 128 + nn];
      WT[idx] = f2bf(val);
    } else {
      int j = idx - 512 * 128;
      int n = j >> 7, k = j & 127;
      WoT[j] = f2bf(Wo[k * 128 + n]);
    }
    return;
  }
  int wv = t >> 6, lane = t & 63;
  int n = lane & 15, g = lane >> 4;
  int myrow = blockIdx.x * 32 + wv * 16 + n;
  const float* rp = in + (size_t)myrow * 128;

  float xv[32];
  float sm = 0.f, ssm = 0.f;
  #pragma unroll
  for (int kc = 0; kc < 4; kc++)
    #pragma unroll
    for (int pr = 0; pr < 2; pr++) {
      float4 v = *(const float4*)(rp + kc * 32 + g * 8 + pr * 4);
      int o = kc * 8 + pr * 4;
      xv[o] = v.x; xv[o+1] = v.y; xv[o+2] = v.z; xv[o+3] = v.w;
      sm  += v.x + v.y + v.z + v.w;
      ssm += v.x*v.x + v.y*v.y + v.z*v.z + v.w*v.w;
    }
  sm  += __shfl_xor(sm, 16, 64);  sm  += __shfl_xor(sm, 32, 64);
  ssm += __shfl_xor(ssm, 16, 64); ssm += __shfl_xor(ssm, 32, 64);
  float mu  = sm * (1.0f / 128.0f);
  float var = ssm * (1.0f / 128.0f) - mu * mu;
  float rs  = rsqrtf(var + 1e-5f);
  float p0 = 0.f, p1 = 0.f, p2 = 0.f, p3 = 0.f;
  #pragma unroll
  for (int kc = 0; kc < 4; kc++)
    #pragma unroll
    for (int pr = 0; pr < 2; pr++) {
      int c0 = kc * 32 + g * 8 + pr * 4;
      float4 g4 = *(const float4*)(gamma + c0);
      float4 b4 = *(const float4*)(beta + c0);
      int o = kc * 8 + pr * 4;
      #pragma unroll
      for (int r = 0; r < 4; r++) {
        float xn = (xv[o + r] - mu) * rs * (&g4.x)[r] + (&b4.x)[r];
        xv[o + r] = xn;
        float4 w = ((const float4*)Wb)[c0 + r];
        p0 += xn * w.x; p1 += xn * w.y; p2 += xn * w.z; p3 += xn * w.w;
      }
    }
  // xln store: one 16B uint4 per kc chunk (8 bf16)
  #pragma unroll
  for (int kc = 0; kc < 4; kc++) {
    int o = kc * 8;
    uint4 px;
    px.x = (unsigned int)f2bf(xv[o])     | ((unsigned int)f2bf(xv[o + 1]) << 16);
    px.y = (unsigned int)f2bf(xv[o + 2]) | ((unsigned int)f2bf(xv[o + 3]) << 16);
    px.z = (unsigned int)f2bf(xv[o + 4]) | ((unsigned int)f2bf(xv[o + 5]) << 16);
    px.w = (unsigned int)f2bf(xv[o + 6]) | ((unsigned int)f2bf(xv[o + 7]) << 16);
    *(uint4*)(xln + (size_t)myrow * 128 + kc * 32 + g * 8) = px;
  }
  p0 += __shfl_xor(p0, 16, 64); p0 += __shfl_xor(p0, 32, 64);
  p1 += __shfl_xor(p1, 16, 64); p1 += __shfl_xor(p1, 32, 64);
  p2 += __shfl_xor(p2, 16, 64); p2 += __shfl_xor(p2, 32, 64);
  p3 += __shfl_xor(p3, 16, 64); p3 += __shfl_xor(p3, 32, 64);
  if (g == 0) {
    const float l2e = 1.4426950408889634f;
    biasB[0 * NPOS + myrow] = f2bf(p0 * l2e);
    biasB[1 * NPOS + myrow] = f2bf(p1 * l2e);
    biasB[2 * NPOS + myrow] = f2bf(p2 * l2e);
    biasB[3 * NPOS + myrow] = f2bf(p3 * l2e);
  }
}

// ---------------- K2: head-slice proj + attention + gate ----------------
// R9: EXACT R5 revert (measured 75.4us, VGPR 60). Ledger: every 3-blocks/CU
// attempt failed — (512,3) => 84 VGPR + scratch spills (hbm 42->198MB, R7);
// Q-in-regs => VGPR 128, wave cap halves (R8); reg-PV => VGPR 92 (R6).
// Do NOT touch launch bounds, qstg, or the PV LDS round-trip.
#define KS 40    // Klds row stride (ushorts; 80B, 16B-aligned)
#define VS 264   // VTlds row stride (ushorts; keys 256 + 8 pad, 16B-aligned)
#define QS 40    // qstg row stride
#define PST 40   // P-stage row stride
__global__ __launch_bounds__(512, 2) void k_attn2(
    const ushort* __restrict__ xln, const ushort* __restrict__ WT,
    const float* __restrict__ bg, const ushort* __restrict__ biasB,
    ushort* __restrict__ gctx) {
  __shared__ __align__(16) ushort Klds[256 * KS];    // 20480 B
  __shared__ __align__(16) ushort VTlds[32 * VS];    // 16896 B
  __shared__ __align__(16) ushort qstg[8][32 * QS];  // 20480 B
  __shared__ __align__(16) ushort pstg[8][16 * PST]; // 10240 B
  int i = blockIdx.x & 255, h = blockIdx.x >> 8;     // XCD-friendly remap
  int t = threadIdx.x, wv = t >> 6, lane = t & 63;
  int n = lane & 15, g = lane >> 4;
  int r0 = wv * 32;

  // ---- phase A: load LN'd rows as MFMA a-frags (bf16, direct) ----
  bf16x8 a[2][4];
  const ushort* xb = xln + ((size_t)i * 256 + r0) * 128;
  #pragma unroll
  for (int c = 0; c < 2; c++)
    #pragma unroll
    for (int kc = 0; kc < 4; kc++)
      a[c][kc] = *(const bf16x8*)(xb + (size_t)(c * 16 + n) * 128 + kc * 32 + g * 8);

  // ---- phase A2: 4 head-slice projections (32 cols each) ----
  f32x4 gs[2][2];   // gate (sigmoid applied), lane-mapped same as PV output
  #pragma unroll
  for (int sect = 0; sect < 4; sect++) {
    bf16x8 b[2][4];
    #pragma unroll
    for (int ntl = 0; ntl < 2; ntl++)
      #pragma unroll
      for (int kc = 0; kc < 4; kc++)
        b[ntl][kc] = *(const bf16x8*)(WT + (size_t)(sect * 128 + h * 32 + ntl * 16 + n) * 128 + kc * 32 + g * 8);
    #pragma unroll
    for (int c = 0; c < 2; c++) {
      f32x4 acc[2];
      #pragma unroll
      for (int ntl = 0; ntl < 2; ntl++) {
        f32x4 cc = {0.f, 0.f, 0.f, 0.f};
        #pragma unroll
        for (int kc = 0; kc < 4; kc++)
          cc = __builtin_amdgcn_mfma_f32_16x16x32_bf16(a[c][kc], b[ntl][kc], cc, 0, 0, 0);
        acc[ntl] = cc;
      }
      // acc[ntl][r] = proj[row r0+c*16+g*4+r][dim ntl*16+n] (head-local dim)
      if (sect == 0) {          // Q -> wave-private LDS [query][dim]
        #pragma unroll
        for (int ntl = 0; ntl < 2; ntl++)
          #pragma unroll
          for (int r = 0; r < 4; r++)
            qstg[wv][(c * 16 + g * 4 + r) * QS + ntl * 16 + n] = f2bf(acc[ntl][r]);
      } else if (sect == 1) {   // K -> shared LDS [key][dim]
        #pragma unroll
        for (int ntl = 0; ntl < 2; ntl++)
          #pragma unroll
          for (int r = 0; r < 4; r++)
            Klds[(r0 + c * 16 + g * 4 + r) * KS + ntl * 16 + n] = f2bf(acc[ntl][r]);
      } else if (sect == 2) {   // V -> shared LDS transposed [dim][key]
        #pragma unroll
        for (int ntl = 0; ntl < 2; ntl++) {
          uint2 vp;
          vp.x = (unsigned int)f2bf(acc[ntl][0]) | ((unsigned int)f2bf(acc[ntl][1]) << 16);
          vp.y = (unsigned int)f2bf(acc[ntl][2]) | ((unsigned int)f2bf(acc[ntl][3]) << 16);
          *(uint2*)(&VTlds[(ntl * 16 + n) * VS + r0 + c * 16 + g * 4]) = vp;
        }
      } else {                  // gate: keep in registers
        #pragma unroll
        for (int ntl = 0; ntl < 2; ntl++)
          #pragma unroll
          for (int r = 0; r < 4; r++)
            gs[c][ntl][r] = 1.0f / (1.0f + __expf(-(acc[ntl][r] + bg[h * 32 + ntl * 16 + n])));
      }
    }
  }
  __syncthreads();

  // ---- phase B: attention for the wave's 32 queries (2 tiles of 16) ----
  const ushort* bb = biasB + (size_t)h * NPOS;
  ushort* Pw = pstg[wv];
  #pragma unroll
  for (int tt = 0; tt < 2; tt++) {
    int j0 = r0 + tt * 16;
    bf16x8 bq = *(const bf16x8*)(&qstg[wv][(tt * 16 + n) * QS + g * 8]);
    // hoist all 16 bias loads (independent, one vmcnt train)
    uint2 bv[16];
    #pragma unroll
    for (int kt = 0; kt < 16; kt++)
      bv[kt] = *(const uint2*)(bb + (size_t)(j0 + n) * 256 + kt * 16 + g * 4);
    f32x4 s[16];
    #pragma unroll
    for (int kt = 0; kt < 16; kt++) {
      bf16x8 ak = *(const bf16x8*)(&Klds[(kt * 16 + n) * KS + g * 8]);
      f32x4 cc;
      cc[0] = lo_bf(bv[kt].x); cc[1] = hi_bf(bv[kt].x);
      cc[2] = lo_bf(bv[kt].y); cc[3] = hi_bf(bv[kt].y);
      s[kt] = __builtin_amdgcn_mfma_f32_16x16x32_bf16(ak, bq, cc, 0, 0, 0);
    }
    // softmax: exp2 (log2e pre-folded), no max-sub (scores bounded ~|2|)
    f32x4 a4 = {0.f, 0.f, 0.f, 0.f};
    #pragma unroll
    for (int kt = 0; kt < 16; kt++) {
      #pragma unroll
      for (int r = 0; r < 4; r++) s[kt][r] = EXP2F(s[kt][r]);
      a4 += s[kt];
    }
    float smm = (a4[0] + a4[1]) + (a4[2] + a4[3]);
    smm += __shfl_xor(smm, 16, 64);
    smm += __shfl_xor(smm, 32, 64);
    float inv = RCPF(smm);
    // PV via wave-private LDS round trip (in-order DS pipe, no barriers)
    f32x4 ctx0 = {0.f, 0.f, 0.f, 0.f}, ctx1 = {0.f, 0.f, 0.f, 0.f};
    #pragma unroll
    for (int c8 = 0; c8 < 8; c8++) {
      #pragma unroll
      for (int t2 = 0; t2 < 2; t2++) {
        int kt = c8 * 2 + t2;
        uint2 pp;
        pp.x = permpack(s[kt][1] * inv, s[kt][0] * inv);
        pp.y = permpack(s[kt][3] * inv, s[kt][2] * inv);
        *(uint2*)(&Pw[n * PST + t2 * 16 + g * 4]) = pp;   // row=query n, 4 keys
      }
      bf16x8 ap = *(const bf16x8*)(&Pw[n * PST + g * 8]);
      bf16x8 v0 = *(const bf16x8*)(&VTlds[(size_t)n * VS + c8 * 32 + g * 8]);
      bf16x8 v1 = *(const bf16x8*)(&VTlds[(size_t)(16 + n) * VS + c8 * 32 + g * 8]);
      ctx0 = __builtin_amdgcn_mfma_f32_16x16x32_bf16(ap, v0, ctx0, 0, 0, 0);
      ctx1 = __builtin_amdgcn_mfma_f32_16x16x32_bf16(ap, v1, ctx1, 0, 0, 0);
    }
    // gate in registers (identical lane mapping), direct global store
    #pragma unroll
    for (int r = 0; r < 4; r++) {
      size_t pos = (size_t)i * 256 + j0 + g * 4 + r;
      gctx[pos * 128 + h * 32 + n]      = f2bf(ctx0[r] * gs[tt][0][r]);
      gctx[pos * 128 + h * 32 + 16 + n] = f2bf(ctx1[r] * gs[tt][1][r]);
    }
  }
}

// ---------------- K3: out-proj + bias + residual ----------------
// barrier-free, LDS-free. Operand-swapped MFMA (A=Wo fragment, B=ctx
// fragment) -> lane(n,g) holds out[row0+n][ntl*16+g*4..+3] -> direct
// coalesced f32x4 residual-add store. 256 thr, 64 rows/block, grid 1024.
__global__ __launch_bounds__(256, 4) void k_out(
    const ushort* __restrict__ gctx, const ushort* __restrict__ WoT,
    const float* __restrict__ bo, const float* __restrict__ in0,
    float* __restrict__ out) {
  int t = threadIdx.x, wv = t >> 6, lane = t & 63;
  int n = lane & 15, g = lane >> 4;
  int row0 = blockIdx.x * 64 + wv * 16;
  bf16x8 cfr[4];
  #pragma unroll
  for (int kc = 0; kc < 4; kc++)
    cfr[kc] = *(const bf16x8*)(gctx + (size_t)(row0 + n) * 128 + kc * 32 + g * 8);
  size_t rowg = (size_t)row0 + n;
  #pragma unroll
  for (int ntl = 0; ntl < 8; ntl++) {
    f32x4 acc = {0.f, 0.f, 0.f, 0.f};
    #pragma unroll
    for (int kc = 0; kc < 4; kc++) {
      bf16x8 wo = *(const bf16x8*)(WoT + (size_t)(ntl * 16 + n) * 128 + kc * 32 + g * 8);
      acc = __builtin_amdgcn_mfma_f32_16x16x32_bf16(wo, cfr[kc], acc, 0, 0, 0);
    }
    f32x4 b4 = *(const f32x4*)(bo + ntl * 16 + g * 4);
    size_t o = rowg * 128 + ntl * 16 + g * 4;
    f32x4 r4 = *(const f32x4*)(in0 + o);
    acc[0] += b4[0] + r4[0]; acc[1] += b4[1] + r4[1];
    acc[2] += b4[2] + r4[2]; acc[3] += b4[3] + r4[3];
    *(f32x4*)(out + o) = acc;
  }
}

extern "C" void kernel_launch(void* const* d_in, const int* in_sizes, int n_in,
                              void* d_out, int out_size, void* d_ws, size_t ws_size,
                              hipStream_t stream) {
  const float* in0   = (const float*)d_in[0];
  const float* gamma = (const float*)d_in[1];
  const float* beta  = (const float*)d_in[2];
  const float* Wq    = (const float*)d_in[3];
  const float* Wk    = (const float*)d_in[4];
  const float* Wv    = (const float*)d_in[5];
  const float* Wb    = (const float*)d_in[6];
  const float* Wg    = (const float*)d_in[7];
  const float* bg    = (const float*)d_in[8];
  const float* Wo    = (const float*)d_in[9];
  const float* bo    = (const float*)d_in[10];
  float* out = (float*)d_out;
  char* ws = (char*)d_ws;

  const size_t MB = 1024 * 1024;
  ushort* gctx  = (ushort*)(ws);              // 16 MB: [pos][128]
  ushort* xln   = (ushort*)(ws + 16 * MB);    // 16 MB: LN'd x, bf16 [pos][128]
  ushort* biasB = (ushort*)(ws + 32 * MB);    // 512 KB: [h][j*256+k] * log2e
  ushort* WT    = (ushort*)(ws + 33 * MB);    // 128 KB
  ushort* WoT   = (ushort*)(ws + 33 * MB + 128 * 1024);  // 32 KB

  k_lnpack<<<2688, 128, 0, stream>>>(in0, gamma, beta, Wb, Wq, Wk, Wv, Wg, Wo,
                                     xln, biasB, WT, WoT);
  k_attn2 <<<1024, 512, 0, stream>>>(xln, WT, bg, biasB, gctx);
  k_out   <<<1024, 256, 0, stream>>>(gctx, WoT, bo, in0, out);
}